// Round 9
// baseline (35.270 us; speedup 1.0000x reference)
//
#include <hip/hip_runtime.h>

// CTC forward loss, B=512, T=512 (Tp=510 after [:,2:,:]), C=96, L=64, S=129.
// Round 9: producer/consumer wave split. Block = 128 threads (2 waves) per
// batch element.
//   wave 1 (producer): gathers pl[t][l] = p[t][label_l], pb[t] = p[t][blank]
//     for 64-step batches into named-f8 register sets, ds_writes them into a
//     double-buffered LDS pane. Eats all HBM latency / vmcnt stalls; loads
//     for batch m+1 are issued one full phase before their ds_write.
//   wave 0 (consumer): the validated r8 DP chain (per-lane scaled linear
//     space, packed f2 state, DPP wave_shr1 neighbor, renorm every 4 steps,
//     zero transcendentals) with operands read from LDS one 8-step group
//     ahead. ZERO VMEM instructions on the DP wave.
//   sync: __syncthreads() per 64-step phase (8 barriers), classic
//     double-buffer: phase m producer writes buf[m%2], consumer eats
//     batch m-1 from buf[(m-1)%2].
// log-softmax normalizer: sum_c(p+EPS) == 1 + C*EPS exactly -> constant.

constexpr int   T_    = 512;
constexpr int   C_    = 96;
constexpr int   L_    = 64;
constexpr int   TP_   = 510;          // T - 2
constexpr float EPS_  = 1e-7f;
constexpr float LN2_  = 0.69314718055994530942f;
constexpr float LSE1_ = 1.3849806e-5f;   // log2(1 + C_*EPS_)

typedef float f8 __attribute__((ext_vector_type(8)));
typedef float f2 __attribute__((ext_vector_type(2)));

__device__ __forceinline__ float flog2(float x) {
#if __has_builtin(__builtin_amdgcn_logf)
  return __builtin_amdgcn_logf(x);
#else
  return log2f(x);
#endif
}
__device__ __forceinline__ float fexp2(float x) {
#if __has_builtin(__builtin_amdgcn_exp2f)
  return __builtin_amdgcn_exp2f(x);
#else
  return exp2f(x);
#endif
}
__device__ __forceinline__ float fldexp(float x, int n) {
#if __has_builtin(__builtin_amdgcn_ldexpf)
  return __builtin_amdgcn_ldexpf(x, n);
#else
  return __builtin_ldexpf(x, n);
#endif
}

template<int CTRL, int RM, int BM, bool BC>
__device__ __forceinline__ float dppf(float old_, float src) {
  return __int_as_float(__builtin_amdgcn_update_dpp(
      __float_as_int(old_), __float_as_int(src), CTRL, RM, BM, BC));
}
template<int CTRL, int RM, int BM, bool BC>
__device__ __forceinline__ int dppi(int old_, int src) {
  return __builtin_amdgcn_update_dpp(old_, src, CTRL, RM, BM, BC);
}

// log2(2^x + 2^y) — readout only
__device__ __forceinline__ float lae2(float x, float y) {
  float m = fmaxf(x, y);
  return m + flog2(1.f + fexp2(-fabsf(x - y)));
}

// ---- producer: gather 8 t's into a named f8 ring (literal fields) ----
#define PG8(R, TB) { \
  R.s0 = gl((TB)+0); R.s1 = gl((TB)+1); R.s2 = gl((TB)+2); R.s3 = gl((TB)+3); \
  R.s4 = gl((TB)+4); R.s5 = gl((TB)+5); R.s6 = gl((TB)+6); R.s7 = gl((TB)+7); }

#define PLOADB(S, TB) { \
  PG8(S##0, (TB)+0);  PG8(S##1, (TB)+8);  PG8(S##2, (TB)+16); PG8(S##3, (TB)+24); \
  PG8(S##4, (TB)+32); PG8(S##5, (TB)+40); PG8(S##6, (TB)+48); PG8(S##7, (TB)+56); \
  q##S = glb((TB) + l); }

#define PW8(R, PH, TI) { \
  plb[PH][(TI)+0][l] = R.s0; plb[PH][(TI)+1][l] = R.s1; \
  plb[PH][(TI)+2][l] = R.s2; plb[PH][(TI)+3][l] = R.s3; \
  plb[PH][(TI)+4][l] = R.s4; plb[PH][(TI)+5][l] = R.s5; \
  plb[PH][(TI)+6][l] = R.s6; plb[PH][(TI)+7][l] = R.s7; }

#define PWRITEB(S, PH) { \
  PW8(S##0, PH, 0)  PW8(S##1, PH, 8)  PW8(S##2, PH, 16) PW8(S##3, PH, 24) \
  PW8(S##4, PH, 32) PW8(S##5, PH, 40) PW8(S##6, PH, 48) PW8(S##7, PH, 56) \
  pbb[PH][l] = q##S; }

// ---- consumer: ds-read one 8-step group into rings ----
#define DSR8(PH, J, PL, PB) { \
  PL.s0 = plb[PH][(J)*8+0][l]; PB.s0 = pbb[PH][(J)*8+0]; \
  PL.s1 = plb[PH][(J)*8+1][l]; PB.s1 = pbb[PH][(J)*8+1]; \
  PL.s2 = plb[PH][(J)*8+2][l]; PB.s2 = pbb[PH][(J)*8+2]; \
  PL.s3 = plb[PH][(J)*8+3][l]; PB.s3 = pbb[PH][(J)*8+3]; \
  PL.s4 = plb[PH][(J)*8+4][l]; PB.s4 = pbb[PH][(J)*8+4]; \
  PL.s5 = plb[PH][(J)*8+5][l]; PB.s5 = pbb[PH][(J)*8+5]; \
  PL.s6 = plb[PH][(J)*8+6][l]; PB.s6 = pbb[PH][(J)*8+6]; \
  PL.s7 = plb[PH][(J)*8+7][l]; PB.s7 = pbb[PH][(J)*8+7]; }

#define ST8(PL, PB) { renormS(); \
  stepS(PL.s0,PB.s0); stepS(PL.s1,PB.s1); stepS(PL.s2,PB.s2); stepS(PL.s3,PB.s3); \
  renormS(); \
  stepS(PL.s4,PB.s4); stepS(PL.s5,PB.s5); stepS(PL.s6,PB.s6); stepS(PL.s7,PB.s7); }

#define GD8(T0, PL, PB) { \
  if ((T0)+0 < tmax) stepF(PL.s0,PB.s0); \
  if ((T0)+1 < tmax) stepF(PL.s1,PB.s1); \
  if ((T0)+2 < tmax) stepF(PL.s2,PB.s2); \
  if ((T0)+3 < tmax) stepF(PL.s3,PB.s3); \
  if ((T0)+4 < tmax) stepF(PL.s4,PB.s4); \
  if ((T0)+5 < tmax) stepF(PL.s5,PB.s5); \
  if ((T0)+6 < tmax) stepF(PL.s6,PB.s6); \
  if ((T0)+7 < tmax) stepF(PL.s7,PB.s7); }

#define COMPG(G, PL, PB) { const int _t0 = 1 + 8*(G); \
  if ((G) >= 8 && (_t0 + 7) < tmax) ST8(PL, PB) else GD8(_t0, PL, PB) }

#define CONSUME(PH, GB) { \
  DSR8(PH, 0, plA, pbA); \
  DSR8(PH, 1, plB, pbB); COMPG((GB)+0, plA, pbA); \
  DSR8(PH, 2, plA, pbA); COMPG((GB)+1, plB, pbB); \
  DSR8(PH, 3, plB, pbB); COMPG((GB)+2, plA, pbA); \
  DSR8(PH, 4, plA, pbA); COMPG((GB)+3, plB, pbB); \
  DSR8(PH, 5, plB, pbB); COMPG((GB)+4, plA, pbA); \
  DSR8(PH, 6, plA, pbA); COMPG((GB)+5, plB, pbB); \
  DSR8(PH, 7, plB, pbB); COMPG((GB)+6, plA, pbA); \
                         COMPG((GB)+7, plB, pbB); }

__global__ __launch_bounds__(128, 1) void ctc_fwd(
    const int* __restrict__ y_true, const float* __restrict__ y_pred,
    const int* __restrict__ input_len, const int* __restrict__ label_len,
    float* __restrict__ out)
{
  __shared__ float plb[2][64][64];   // [phase][t in batch][lane]  (32 KB)
  __shared__ float pbb[2][64];       // [phase][t in batch]        (512 B)
  const int tid = threadIdx.x;
  const int wid = tid >> 6;
  const int l   = tid & 63;
  const int b   = blockIdx.x;

  const float* __restrict__ rp = y_pred + (size_t)b * T_ * C_ + 2 * C_;
  const int  lab     = y_true[b * L_ + l];        // label of odd state 2l+1
  const int  labPrev = __shfl_up(lab, 1);
  const float skipM  = (l >= 1 && lab != labPrev) ? 1.f : 0.f;
  const int  ilen    = input_len[b];
  const int  llen    = label_len[b];               // in [16, 64]
  const int  tmax    = ilen < TP_ ? ilen : TP_;

  const float* __restrict__ colL = rp + lab;       // per-lane column
  const float* __restrict__ colB = rp + (C_ - 1);  // uniform (blank) column

  auto gl  = [&](int t) -> float { int tc = t < TP_ ? t : TP_ - 1; return colL[(size_t)tc * C_]; };
  auto glb = [&](int t) -> float { int tc = t < TP_ ? t : TP_ - 1; return colB[(size_t)tc * C_]; };

  // per-lane scaled-linear state (consumer wave): alpha = m * 2^e
  f2    mm;
  float mX = 0.f;
  int   e = 0, d = 0;
  mm.x = (wid == 0 && l == 0) ? (colB[0] + EPS_) : 0.f;
  mm.y = (wid == 0 && l == 0) ? (colL[0] + EPS_) : 0.f;

  auto run = [&](auto hasC) {
    constexpr bool H128 = decltype(hasC)::value;

    // fill/tail step: per-step renorm + empty-lane exponent adoption (r8)
    auto stepF = [&](float pl, float pb) {
      float plE = pl + EPS_, pbE = pb + EPS_;
      int   en  = dppi<0x138, 0xf, 0xf, false>(0, e);      // wave_shr1
      float m1  = dppf<0x138, 0xf, 0xf, false>(0.f, mm.y);
      int   dd  = en - e;  dd = dd < 120 ? dd : 120;
      float a1  = fldexp(m1, dd);
      float nE  = (mm.x + a1) * pbE;
      float nO  = fmaf(a1, skipM, mm.y + mm.x) * plE;
      float nX = 0.f, mx;
      if constexpr (H128) { nX = (mX + mm.y) * pbE; mx = fmaxf(fmaxf(nE, nO), nX); }
      else                { mx = fmaxf(nE, nO); }
      int  kb = __float_as_int(mx) >> 23;
      int  ks = 127 - kb;
      bool z  = (mx == 0.f);
      e  = z ? en : (e + kb - 127);
      mm.x = fldexp(nE, ks);
      mm.y = fldexp(nO, ks);
      if constexpr (H128) mX = fldexp(nX, ks);
    };

    // steady step: packed pair update; e, d frozen since last renormS (r8)
    auto stepS = [&](float pl, float pb) {
      f2 p2;  p2.x = pb + EPS_;  p2.y = pl + EPS_;
      float m1 = dppf<0x138, 0xf, 0xf, false>(0.f, mm.y);
      float a1 = fldexp(m1, d);
      float t  = fmaf(a1, skipM, mm.x);
      if constexpr (H128) mX = (mX + mm.y) * p2.x;
      f2 ad;  ad.x = a1;  ad.y = t;
      mm = (mm + ad) * p2;   // v_pk_add_f32 + v_pk_mul_f32
    };

    auto renormS = [&]() {
      float mx = fmaxf(mm.x, mm.y);
      if constexpr (H128) mx = fmaxf(mx, mX);
      int kb = __float_as_int(mx) >> 23;   // mx > 0, normal in steady phase
      int ks = 127 - kb;
      e += kb - 127;
      mm.x = fldexp(mm.x, ks);
      mm.y = fldexp(mm.y, ks);
      if constexpr (H128) mX = fldexp(mX, ks);
      int en = dppi<0x138, 0xf, 0xf, false>(0, e);
      int dd = en - e;  d = dd < 120 ? dd : 120;
    };

    // producer register sets (named, literal fields only)
    f8 A0,A1,A2,A3,A4,A5,A6,A7, C0,C1,C2,C3,C4,C5,C6,C7;
    float qA, qC;
    // consumer rings
    f8 plA, plB, pbA, pbB;

    if (wid == 1) { PLOADB(A, 1) PLOADB(C, 65) }

#pragma unroll 1
    for (int mp = 0; mp < 8; ++mp) {
      if (wid == 1) {
        if (mp & 1) {
          if (mp < 7) PLOADB(A, 1 + 64 * (mp + 1))   // batch mp+1 -> A
          PWRITEB(C, 1)                              // batch mp (odd) -> buf1
        } else {
          if (mp >= 2) PLOADB(C, 1 + 64 * (mp + 1))  // batch mp+1 -> C
          PWRITEB(A, 0)                              // batch mp (even) -> buf0
        }
      } else if (mp >= 1) {
        const int ph = (mp - 1) & 1;
        const int gb = (mp - 1) * 8;
        CONSUME(ph, gb)
      }
      __syncthreads();
    }
    if (wid == 0) CONSUME(1, 56)     // batch 7 from buf1
  };

  if (llen >= 64) run(std::integral_constant<bool, true>{});
  else            run(std::integral_constant<bool, false>{});

  // readout (consumer wave): log2(alpha) = log2(m) + e
  if (wid == 0) {
    float ef  = (float)e;
    float lgE = flog2(mm.x) + ef;
    float lgO = flog2(mm.y) + ef;
    float aL;
    if (llen >= 64) { float lgX = flog2(mX) + ef; aL = __shfl(lgX, 63); }
    else            { aL = __shfl(lgE, llen); }
    float aP = __shfl(lgO, llen - 1);
    if (l == 0)
      out[b] = -LN2_ * (lae2(aL, aP) - (float)tmax * LSE1_);
  }
}

extern "C" void kernel_launch(void* const* d_in, const int* in_sizes, int n_in,
                              void* d_out, int out_size, void* d_ws, size_t ws_size,
                              hipStream_t stream) {
  const int*   y_true = (const int*)d_in[0];
  const float* y_pred = (const float*)d_in[1];
  const int*   ilen   = (const int*)d_in[2];
  const int*   llen   = (const int*)d_in[3];
  float*       outp   = (float*)d_out;
  const int    B      = out_size;   // 512
  hipLaunchKernelGGL(ctc_fwd, dim3(B), dim3(128), 0, stream,
                     y_true, y_pred, ilen, llen, outp);
}